// Round 6
// baseline (115.668 us; speedup 1.0000x reference)
//
#include <hip/hip_runtime.h>

#define HW    256
#define HW2   (HW*HW)
#define KTAPS 25
#define TW    32          // 32-px wave rows = 128 B full-line kern loads AND output stores
#define TH    4           // 64 lanes = 16 cols x 4 rows, 2 px/thread (50-VGPR weights)
#define LW    36          // LDS row length (TW + 4); 144 B rows
#define LH    8           // TH + 4
#define NEL   (LW*LH)     // 288
#define NSTG  5           // ceil(288/64); covers 320 slots (overrun clamped-valid, buffer sized)
#define BUFSZ (NSTG*64)   // 320 floats per ring buffer
#define NRING 6
#define DEPTH 4           // stage(cc+4) overwrites slot (cc-2)%6: TWO-iteration read->overwrite
                          // gap, same safety proof as the verified DEPTH=2/ring-4 version:
                          // store(cc-2) (pinned before the W(cc-1) asm by its memory clobber)
                          // data-depends on ds_read(cc-2), so slot reads are complete before
                          // the overwriting DMA can issue. Round-3's race needed a ONE-gap.
#define CPB   16          // channels per block (channel-split = 2): softmax amortized 2x,
                          // grid 4096 = exactly 16 blocks/CU at (64,4) -> one dispatch batch
#define C     32

// Issue the 5 async global->LDS loads for one channel tile.
// Global source is per-lane (clamped edge-replicate folded into soff);
// LDS dest is wave-uniform base + lane*4, matching idx = k*64 + lane.
__device__ __forceinline__ void stage(const float* __restrict__ src, float* dst,
                                      const int* __restrict__ soff) {
#pragma unroll
    for (int k = 0; k < NSTG; ++k)
        __builtin_amdgcn_global_load_lds(
            (const __attribute__((address_space(1))) unsigned int*)(src + soff[k]),
            (__attribute__((address_space(3))) unsigned int*)(dst + k * 64),
            4, 0, 0);
}

// (64,4): cap 128 regs, live set ~90 (50 wt + 5 soff + accum/addressing) -> no spill
// (round-1's spill was the 4px kernel needing ~170). 4 waves/SIMD = 16 waves/CU =
// exactly the 4096-block grid resident in one batch.
__global__ __launch_bounds__(64, 4) void ddown_kernel(
    const float* __restrict__ x,
    const float* __restrict__ kern,
    float* __restrict__ out)
{
    __shared__ __align__(16) float xt[NRING][BUFSZ];   // 6 * 1280 B = 7680 B

    const int lane = threadIdx.x;      // one wave per block: no __syncthreads anywhere
    const int txq  = lane & 15;        // 16 thread-columns of 2 outputs
    const int ty   = lane >> 4;        // 4 rows
    const int w0   = blockIdx.x * TW;
    const int h0   = blockIdx.y * TH;
    const int b    = blockIdx.z >> 1;
    const int c0   = (blockIdx.z & 1) * CPB;

    const int h = h0 + ty;
    const int w = w0 + txq * 2;

    const float* xb = x + (size_t)(b * C + c0) * HW2;

    // Per-lane clamped source offsets, hoisted out of the channel loop.
    // k=4 lanes 32..63 -> idx 288..319 -> i=8 (one past halo), clamped-valid pad slots.
    int soff[NSTG];
#pragma unroll
    for (int k = 0; k < NSTG; ++k) {
        int idx = lane + k * 64;
        int i   = idx / LW;
        int j   = idx - i * LW;
        int hh  = min(max(h0 + i - 2, 0), HW - 1);
        int ww  = min(max(w0 + j - 2, 0), HW - 1);
        soff[k] = hh * HW + ww;
    }

    // Prologue: channels 0..3 in flight before the softmax phase even starts.
    stage(xb,           xt[0], soff);
    stage(xb + HW2,     xt[1], soff);
    stage(xb + 2 * HW2, xt[2], soff);
    stage(xb + 3 * HW2, xt[3], soff);

    // ---- softmax weights for this thread's 2 pixels (unnormalized; fold 1/S later) ----
    // 25 float2 loads into 50 distinct VGPRs: independent, back-to-back, 128 B wave rows.
    const float* kb = kern + (size_t)b * KTAPS * HW2 + h * HW + w;
    float2 wt[KTAPS];
    float sx = 0.f, sy = 0.f;
#pragma unroll
    for (int j = 0; j < KTAPS; ++j) {
        float2 v = *(const float2*)(kb + (size_t)j * HW2);
        v.x = __expf(v.x); v.y = __expf(v.y);
        sx += v.x; sy += v.y;
        wt[j] = v;
    }
    const float ix = 1.f / sx, iy = 1.f / sy;

    float* ob = out + (size_t)(b * C + c0) * HW2 + h * HW + w;

    // Exact FIFO vmcnt accounting (in-order retirement). N(cc) = number of VMEM ops
    // GUARANTEED issued after stage(cc)'s last load: stages can't cross the per-
    // iteration asm (memory clobber); a store in the SAME window as a stage is
    // excluded (ordering vs the stage not guaranteed) -> counts are safe under any
    // legal compiler ordering. Issue order: S0..S3, kern(25), then per cc:
    // [S(cc+4)] W(cc) reads st(cc).
    //   W0: S1..S3 + kern + S4               = 45
    //   W1: S2,S3 + kern + S4,S5 + st0       = 46
    //   W2: S3 + kern + S4..S6 + st0,st1     = 47
    //   W3: kern + S4..S7 + st0..st2         = 48
    //   W4..W11: S(cc+1)..S(cc+4) + 3 stores = 23
    //   W12: S13..S15 + st9..st11            = 18
    //   W13: S14,S15  + st10..st12           = 13
    //   W14: S15      + st11..st13           = 8
    //   W15:            st12..st14           = 3
#pragma unroll
    for (int cc = 0; cc < CPB; ++cc) {
        if (cc + DEPTH < CPB) stage(xb + (size_t)(cc + DEPTH) * HW2, xt[(cc + DEPTH) % NRING], soff);

        if      (cc == 0)  asm volatile("s_waitcnt vmcnt(45)" ::: "memory");
        else if (cc == 1)  asm volatile("s_waitcnt vmcnt(46)" ::: "memory");
        else if (cc == 2)  asm volatile("s_waitcnt vmcnt(47)" ::: "memory");
        else if (cc == 3)  asm volatile("s_waitcnt vmcnt(48)" ::: "memory");
        else if (cc <= 11) asm volatile("s_waitcnt vmcnt(23)" ::: "memory");
        else if (cc == 12) asm volatile("s_waitcnt vmcnt(18)" ::: "memory");
        else if (cc == 13) asm volatile("s_waitcnt vmcnt(13)" ::: "memory");
        else if (cc == 14) asm volatile("s_waitcnt vmcnt(8)"  ::: "memory");
        else               asm volatile("s_waitcnt vmcnt(3)"  ::: "memory");

        const float* xc = xt[cc % NRING];
        float ax = 0.f, ay = 0.f;
#pragma unroll
        for (int di = 0; di < 5; ++di) {
            const float* row = &xc[(ty + di) * LW + txq * 2];
            float2 pa = *(const float2*)(row);      // ds_read_b64
            float2 pb = *(const float2*)(row + 2);
            float2 pc = *(const float2*)(row + 4);
            float w6[6] = {pa.x, pa.y, pb.x, pb.y, pc.x, pc.y};
#pragma unroll
            for (int dj = 0; dj < 5; ++dj) {
                float2 wv = wt[di * 5 + dj];
                ax += wv.x * w6[dj + 0];
                ay += wv.y * w6[dj + 1];
            }
        }
        float2 res = { ax * ix, ay * iy };
        *(float2*)(ob + (size_t)cc * HW2) = res;   // 128 B full-line wave-row stores
    }
}

extern "C" void kernel_launch(void* const* d_in, const int* in_sizes, int n_in,
                              void* d_out, int out_size, void* d_ws, size_t ws_size,
                              hipStream_t stream) {
    const float* x    = (const float*)d_in[0];
    const float* kern = (const float*)d_in[1];
    float* out        = (float*)d_out;

    dim3 grid(HW / TW, HW / TH, 4 * 2);   // (8, 64, 8) = 4096 single-wave blocks
    ddown_kernel<<<grid, 64, 0, stream>>>(x, kern, out);
}

// Round 7
// 112.974 us; speedup vs baseline: 1.0238x; 1.0238x over previous
//
#include <hip/hip_runtime.h>

#define HW    256
#define HW2   (HW*HW)
#define KTAPS 25
#define TW    32          // 32-px wave rows = 128 B full-line kern loads AND output stores
#define TH    4           // 64 lanes = 16 cols x 4 rows, 2 px/thread (50-VGPR weights)
#define LW    40          // halo row covers cols w0-4 .. w0+35 (needed: w0-2..w0+33).
                          // 40 = 4*10: every 4-float group is row-contained AND 16B-aligned
                          // -> interior blocks stage with 2 global_load_lds_dwordx4 per
                          // channel (vs 5 dword DMAs). VMEM instr count is the round-6
                          // theory: 3 neutral pipeline-depth rounds => issue-rate-bound.
#define LH    8           // TH + 4
#define NEL   (LW*LH)     // 320 = exactly 5*64 (edge dword path has zero overrun)
#define BUFSZ 512         // dwordx4 path writes 2*1024 B; overrun rows clamped-valid
#define NRING 4
#define DEPTH 2           // channels in flight. DO NOT RAISE TO 3 on ring-4 (round-3 race):
                          // two-iteration read->overwrite gap is the proven-safe discipline:
                          // store(cc-2), pinned by the asm memory clobbers, data-depends on
                          // ds_read(cc-2), so slot reads complete before the overwriting
                          // DMA issues.
#define CPB   16          // channel-split 2: grid 4096 = 16 blocks/CU at (64,4), one batch
#define C     32

// Interior staging: one channel tile = 2 x 16B-wide async DMA (128 VMEM-lanes each).
__device__ __forceinline__ void stage4(const float* __restrict__ src, float* dst,
                                       const int* __restrict__ soff4) {
#pragma unroll
    for (int k = 0; k < 2; ++k)
        __builtin_amdgcn_global_load_lds(
            (const __attribute__((address_space(1))) unsigned int*)(src + soff4[k]),
            (__attribute__((address_space(3))) unsigned int*)(dst + k * 256),
            16, 0, 0);
}

// Edge staging (blockIdx.x 0 or 7): per-element clamped dword path, 5 DMAs.
__device__ __forceinline__ void stage1(const float* __restrict__ src, float* dst,
                                       const int* __restrict__ soff) {
#pragma unroll
    for (int k = 0; k < 5; ++k)
        __builtin_amdgcn_global_load_lds(
            (const __attribute__((address_space(1))) unsigned int*)(src + soff[k]),
            (__attribute__((address_space(3))) unsigned int*)(dst + k * 64),
            4, 0, 0);
}

// NL = loads per stage (2 interior / 5 edge). vmcnt tables are loads-only counts
// (stores ticking vmcnt only makes the waits stricter -> safe either way).
// Issue order: S0,S1 (prologue), kern(25), then per cc: [S(cc+2)] W(cc) compute store.
//   NL=2: W0 = S1(2)+K(25)+S2(2) = 29; W1 = K+S2+S3 = 29; W2..13 = S(cc+1)+S(cc+2) = 4;
//         W14 = S15 = 2; W15 = 0.
//   NL=5: W0 = 5+25+5 = 35; W1 = 35; W2..13 = 10; W14 = 5; W15 = 0.
template <int NL>
__device__ __forceinline__ void channel_loop(
    const float* __restrict__ xb, float (*xt)[BUFSZ], const int* __restrict__ soff,
    const float2* __restrict__ wt, float ix, float iy,
    float* __restrict__ ob, int ty, int txq)
{
#pragma unroll
    for (int cc = 0; cc < CPB; ++cc) {
        if (cc + DEPTH < CPB) {
            if constexpr (NL == 2)
                stage4(xb + (size_t)(cc + DEPTH) * HW2, xt[(cc + DEPTH) % NRING], soff);
            else
                stage1(xb + (size_t)(cc + DEPTH) * HW2, xt[(cc + DEPTH) % NRING], soff);
        }
        if constexpr (NL == 2) {
            if      (cc <= 1)  asm volatile("s_waitcnt vmcnt(29)" ::: "memory");
            else if (cc <= 13) asm volatile("s_waitcnt vmcnt(4)"  ::: "memory");
            else if (cc == 14) asm volatile("s_waitcnt vmcnt(2)"  ::: "memory");
            else               asm volatile("s_waitcnt vmcnt(0)"  ::: "memory");
        } else {
            if      (cc <= 1)  asm volatile("s_waitcnt vmcnt(35)" ::: "memory");
            else if (cc <= 13) asm volatile("s_waitcnt vmcnt(10)" ::: "memory");
            else if (cc == 14) asm volatile("s_waitcnt vmcnt(5)"  ::: "memory");
            else               asm volatile("s_waitcnt vmcnt(0)"  ::: "memory");
        }

        const float* xc = xt[cc % NRING];
        float ax = 0.f, ay = 0.f;
#pragma unroll
        for (int di = 0; di < 5; ++di) {
            // output col w0+txq*2 needs halo cols (txq*2+dj+2-? ) -> j0 = txq*2+2 under
            // the j -> w0+j-4 mapping; float2 reads stay 8B-aligned (j0 even).
            const float* row = &xc[(ty + di) * LW + txq * 2 + 2];
            float2 pa = *(const float2*)(row);      // ds_read_b64
            float2 pb = *(const float2*)(row + 2);
            float2 pc = *(const float2*)(row + 4);
            float w6[6] = {pa.x, pa.y, pb.x, pb.y, pc.x, pc.y};
#pragma unroll
            for (int dj = 0; dj < 5; ++dj) {
                float2 wv = wt[di * 5 + dj];
                ax += wv.x * w6[dj + 0];
                ay += wv.y * w6[dj + 1];
            }
        }
        float2 res = { ax * ix, ay * iy };
        *(float2*)(ob + (size_t)cc * HW2) = res;   // 128 B full-line wave-row stores
    }
}

// (64,4): cap 128 regs, live set ~95 (50 wt + soff + accum/addressing) -> no spill
// (round-4/5 confirmed WRITE stays at pure-output 32.8 MB at this live set).
__global__ __launch_bounds__(64, 4) void ddown_kernel(
    const float* __restrict__ x,
    const float* __restrict__ kern,
    float* __restrict__ out)
{
    __shared__ __align__(16) float xt[NRING][BUFSZ];   // 4 * 2048 B = 8192 B

    const int lane = threadIdx.x;      // one wave per block: no __syncthreads anywhere
    const int txq  = lane & 15;        // 16 thread-columns of 2 outputs
    const int ty   = lane >> 4;        // 4 rows
    const int w0   = blockIdx.x * TW;
    const int h0   = blockIdx.y * TH;
    const int b    = blockIdx.z >> 1;
    const int c0   = (blockIdx.z & 1) * CPB;

    const int h = h0 + ty;
    const int w = w0 + txq * 2;

    const float* xb = x + (size_t)(b * C + c0) * HW2;
    const bool interior = (blockIdx.x >= 1) && (blockIdx.x <= 6);  // wave-uniform

    int soff[5];   // interior uses [0..1] as the two dwordx4 group offsets
    if (interior) {
        // group m = k*64 + lane covers floats 4m..4m+3 of the tile; row = m/10,
        // col = 4*(m%10); ww = w0 + col - 4 (>=28, <=228: no col clamp needed, 16B-aligned).
        // k=1 overruns to rows 8..12: hh-clamped, lands in buffer floats 256..511.
#pragma unroll
        for (int k = 0; k < 2; ++k) {
            int m  = k * 64 + lane;
            int i  = m / 10;
            int j4 = 4 * (m - i * 10);
            int hh = min(max(h0 + i - 2, 0), HW - 1);
            soff[k] = hh * HW + (w0 + j4 - 4);
        }
        stage4(xb,       xt[0], soff);
        stage4(xb + HW2, xt[1], soff);
    } else {
#pragma unroll
        for (int k = 0; k < 5; ++k) {
            int idx = lane + k * 64;          // 0..319 exactly, no overrun
            int i   = idx / LW;
            int j   = idx - i * LW;
            int hh  = min(max(h0 + i - 2, 0), HW - 1);
            int ww  = min(max(w0 + j - 4, 0), HW - 1);
            soff[k] = hh * HW + ww;
        }
        stage1(xb,       xt[0], soff);
        stage1(xb + HW2, xt[1], soff);
    }

    // ---- softmax weights for this thread's 2 pixels (unnormalized; fold 1/S later) ----
    // 25 float2 loads into 50 distinct VGPRs, 128 B wave rows; latency overlaps the
    // prologue stages above.
    const float* kb = kern + (size_t)b * KTAPS * HW2 + h * HW + w;
    float2 wt[KTAPS];
    float sx = 0.f, sy = 0.f;
#pragma unroll
    for (int j = 0; j < KTAPS; ++j) {
        float2 v = *(const float2*)(kb + (size_t)j * HW2);
        v.x = __expf(v.x); v.y = __expf(v.y);
        sx += v.x; sy += v.y;
        wt[j] = v;
    }
    const float ix = 1.f / sx, iy = 1.f / sy;

    float* ob = out + (size_t)(b * C + c0) * HW2 + h * HW + w;

    if (interior) channel_loop<2>(xb, xt, soff, wt, ix, iy, ob, ty, txq);
    else          channel_loop<5>(xb, xt, soff, wt, ix, iy, ob, ty, txq);
}

extern "C" void kernel_launch(void* const* d_in, const int* in_sizes, int n_in,
                              void* d_out, int out_size, void* d_ws, size_t ws_size,
                              hipStream_t stream) {
    const float* x    = (const float*)d_in[0];
    const float* kern = (const float*)d_in[1];
    float* out        = (float*)d_out;

    dim3 grid(HW / TW, HW / TH, 4 * 2);   // (8, 64, 8) = 4096 single-wave blocks
    ddown_kernel<<<grid, 64, 0, stream>>>(x, kern, out);
}